// Round 2
// baseline (3104.541 us; speedup 1.0000x reference)
//
#include <hip/hip_runtime.h>
#include <hip/hip_bf16.h>

#define D 128

// One thread per (edge, dim). Undirected: scatter feat[dst] into sum[src] and
// feat[src] into sum[dst]. fp32 accumulation via global atomics.
__global__ __launch_bounds__(256) void edge_scatter(
    const int* __restrict__ ei, const float* __restrict__ feat,
    float* __restrict__ nsum, float* __restrict__ cnt, int E) {
    long long tid = (long long)blockIdx.x * blockDim.x + threadIdx.x;
    int e = (int)(tid >> 7);
    if (e >= E) return;
    int d = (int)(tid & 127);
    int src = ei[e];
    int dst = ei[E + e];
    float fs = feat[(size_t)src * D + d];
    float fd = feat[(size_t)dst * D + d];
    atomicAdd(&nsum[(size_t)src * D + d], fd);
    atomicAdd(&nsum[(size_t)dst * D + d], fs);
    if (d == 0) {
        atomicAdd(&cnt[src], 1.0f);
        atomicAdd(&cnt[dst], 1.0f);
    }
}

// 16 rows per block, 256 threads = 2 row-groups x 128 cols.
// combined[r][k] staged in LDS (k<128: self feats; k>=128: neigh mean).
// NOTE: nsum may alias out (Plan B, in-place). Safe because each block reads
// its 16 rows fully into LDS before the barrier, and writes only those same
// rows after it (nodes is the identity permutation in this problem).
__global__ __launch_bounds__(256) void sage_out(
    const int* __restrict__ nodes, const float* __restrict__ feat,
    const float* nsum, const float* __restrict__ cnt,
    const float* __restrict__ W, const float* __restrict__ b,
    float* out, int B) {
    __shared__ float comb[16][256];
    const int t = threadIdx.x;
    const int j = t & 127;
    const int rr = t >> 7;  // 0..1
    const int base = blockIdx.x * 16;

    // Stage combined rows: each of 256 threads loads one element per row.
    for (int r = 0; r < 16; ++r) {
        int row = base + r;
        float v = 0.0f;
        if (row < B) {
            int node = nodes[row];
            if (t < 128) {
                v = feat[(size_t)node * D + t];
            } else {
                float c = cnt[node];
                float inv = 1.0f / fmaxf(c, 1.0f);
                v = nsum[(size_t)node * D + (t - 128)] * inv;
            }
        }
        comb[r][t] = v;
    }
    __syncthreads();

    float acc[8];
    const float bj = b[j];
#pragma unroll
    for (int r = 0; r < 8; ++r) acc[r] = bj;

#pragma unroll 4
    for (int k = 0; k < 256; ++k) {
        float wj = W[(size_t)k * 128 + j];
#pragma unroll
        for (int r = 0; r < 8; ++r) {
            acc[r] += comb[rr + 2 * r][k] * wj;  // LDS broadcast within wave
        }
    }

#pragma unroll
    for (int r = 0; r < 8; ++r) {
        int row = base + rr + 2 * r;
        if (row < B) {
            out[(size_t)row * D + j] = fmaxf(acc[r], 0.0f);
        }
    }
}

extern "C" void kernel_launch(void* const* d_in, const int* in_sizes, int n_in,
                              void* d_out, int out_size, void* d_ws, size_t ws_size,
                              hipStream_t stream) {
    const int* nodes = (const int*)d_in[0];
    const float* feat = (const float*)d_in[1];
    const int* ei = (const int*)d_in[2];
    const float* W = (const float*)d_in[3];
    const float* b = (const float*)d_in[4];
    float* out = (float*)d_out;

    const int B = in_sizes[0];          // 100000 output rows
    const int N = in_sizes[1] / D;      // 100000 feature rows
    const int E = in_sizes[2] / 2;      // 3.2M edges

    const size_t nsum_bytes = (size_t)N * D * sizeof(float);
    const size_t cnt_bytes = (size_t)N * sizeof(float);

    float* nsum;
    float* cnt;
    if (ws_size >= nsum_bytes + cnt_bytes) {
        // Plan A: everything in workspace.
        nsum = (float*)d_ws;
        cnt = nsum + (size_t)N * D;
        hipMemsetAsync(d_ws, 0, nsum_bytes + cnt_bytes, stream);
    } else {
        // Plan B: d_out (fp32, N*D elements) doubles as the sum accumulator;
        // only cnt lives in ws. sage_out then finalizes in place.
        nsum = out;
        cnt = (float*)d_ws;
        hipMemsetAsync(d_out, 0, nsum_bytes, stream);
        hipMemsetAsync(d_ws, 0, cnt_bytes, stream);
    }

    long long tot = (long long)E * 128;
    int blocks = (int)((tot + 255) / 256);
    edge_scatter<<<blocks, 256, 0, stream>>>(ei, feat, nsum, cnt, E);

    sage_out<<<(B + 15) / 16, 256, 0, stream>>>(nodes, feat, nsum, cnt, W, b, out, B);
}

// Round 3
// 1491.757 us; speedup vs baseline: 2.0811x; 2.0811x over previous
//
#include <hip/hip_runtime.h>
#include <hip/hip_bf16.h>

#define D 128

// ---------------- CSR build ----------------

__global__ __launch_bounds__(256) void degree_count(
    const int* __restrict__ ei, int* __restrict__ deg, int E) {
    int e = blockIdx.x * blockDim.x + threadIdx.x;
    if (e >= E) return;
    int src = ei[e];
    int dst = ei[E + e];
    atomicAdd(&deg[src], 1);
    atomicAdd(&deg[dst], 1);
}

// Per-block exclusive scan of 1024 elements (256 threads x 4).
__global__ __launch_bounds__(256) void scan_block(
    const int* __restrict__ deg, int* __restrict__ rowptr,
    int* __restrict__ bsum, int N) {
    __shared__ int lds[256];
    const int t = threadIdx.x;
    const int base = blockIdx.x * 1024 + t * 4;
    int v[4];
#pragma unroll
    for (int k = 0; k < 4; ++k) v[k] = (base + k < N) ? deg[base + k] : 0;
    lds[t] = v[0] + v[1] + v[2] + v[3];
    __syncthreads();
    // Hillis-Steele inclusive scan over 256 thread sums.
    for (int off = 1; off < 256; off <<= 1) {
        int x = (t >= off) ? lds[t - off] : 0;
        __syncthreads();
        lds[t] += x;
        __syncthreads();
    }
    if (t == 255) bsum[blockIdx.x] = lds[255];
    int run = (t > 0) ? lds[t - 1] : 0;
#pragma unroll
    for (int k = 0; k < 4; ++k) {
        if (base + k < N) rowptr[base + k] = run;
        run += v[k];
    }
}

// Serial exclusive scan of the (<=128) block sums. Tiny.
__global__ void scan_aux(int* __restrict__ bsum, int nb) {
    if (threadIdx.x == 0 && blockIdx.x == 0) {
        int run = 0;
        for (int i = 0; i < nb; ++i) {
            int v = bsum[i];
            bsum[i] = run;
            run += v;
        }
    }
}

__global__ __launch_bounds__(256) void scan_finalize(
    int* __restrict__ rowptr, int* __restrict__ cursor,
    const int* __restrict__ bsum, int N, int twoE) {
    int i = blockIdx.x * blockDim.x + threadIdx.x;
    if (i == 0) rowptr[N] = twoE;
    if (i >= N) return;
    int r = rowptr[i] + bsum[i >> 10];
    rowptr[i] = r;
    cursor[i] = r;
}

__global__ __launch_bounds__(256) void csr_fill(
    const int* __restrict__ ei, int* __restrict__ cursor,
    int* __restrict__ col, int E) {
    int e = blockIdx.x * blockDim.x + threadIdx.x;
    if (e >= E) return;
    int src = ei[e];
    int dst = ei[E + e];
    int p = atomicAdd(&cursor[src], 1);
    col[p] = dst;
    int q = atomicAdd(&cursor[dst], 1);
    col[q] = src;
}

// ---------------- fused gather + mean + GEMM + bias + relu ----------------
// Block = 16 output rows. comb[r][0:128) = self feats, comb[r][128:256) = neigh mean.
// Gather: wave-pair (rr = t>>7, uniform per wave) owns node 2*r+rr; 128 lanes
// sweep dims; neighbor loop is wave-uniform -> col loads become scalar loads,
// feat row reads are 256B-coalesced per wave, L3-resident.
__global__ __launch_bounds__(256) void gather_gemm(
    const int* __restrict__ nodes, const float* __restrict__ feat,
    const int* __restrict__ rowptr, const int* __restrict__ col,
    const float* __restrict__ W, const float* __restrict__ b,
    float* __restrict__ out, int B) {
    __shared__ float comb[16][256];
    const int t = threadIdx.x;
    const int j = t & 127;
    const int rr = t >> 7;  // 0..1, uniform per wave
    const int base = blockIdx.x * 16;

    // Self features.
    for (int idx = t; idx < 16 * 128; idx += 256) {
        int r = idx >> 7, jj = idx & 127;
        int row = base + r;
        comb[r][jj] = (row < B) ? feat[(size_t)nodes[row] * D + jj] : 0.0f;
    }

    // Neighbor mean.
    for (int r = 0; r < 8; ++r) {
        int rl = 2 * r + rr;
        int row = base + rl;
        float m = 0.0f;
        if (row < B) {
            int node = nodes[row];
            int s0 = rowptr[node], s1 = rowptr[node + 1];
            float sum0 = 0.f, sum1 = 0.f, sum2 = 0.f, sum3 = 0.f;
            int i = s0;
            for (; i + 3 < s1; i += 4) {
                int n0 = col[i], n1 = col[i + 1], n2 = col[i + 2], n3 = col[i + 3];
                sum0 += feat[(size_t)n0 * D + j];
                sum1 += feat[(size_t)n1 * D + j];
                sum2 += feat[(size_t)n2 * D + j];
                sum3 += feat[(size_t)n3 * D + j];
            }
            for (; i < s1; ++i) sum0 += feat[(size_t)col[i] * D + j];
            int deg = s1 - s0;
            float inv = (deg > 0) ? 1.0f / (float)deg : 0.0f;
            m = ((sum0 + sum1) + (sum2 + sum3)) * inv;
        }
        comb[rl][128 + j] = m;
    }
    __syncthreads();

    float acc[8];
    const float bj = b[j];
#pragma unroll
    for (int r = 0; r < 8; ++r) acc[r] = bj;

#pragma unroll 4
    for (int k = 0; k < 256; ++k) {
        float wj = W[(size_t)k * 128 + j];
#pragma unroll
        for (int r = 0; r < 8; ++r) {
            acc[r] += comb[2 * r + rr][k] * wj;  // LDS broadcast within wave
        }
    }

#pragma unroll
    for (int r = 0; r < 8; ++r) {
        int row = base + 2 * r + rr;
        if (row < B) out[(size_t)row * D + j] = fmaxf(acc[r], 0.0f);
    }
}

// ---------------- fallback (round-2 path) if ws is too small ----------------

__global__ __launch_bounds__(256) void edge_scatter(
    const int* __restrict__ ei, const float* __restrict__ feat,
    float* __restrict__ nsum, float* __restrict__ cnt, int E) {
    long long tid = (long long)blockIdx.x * blockDim.x + threadIdx.x;
    int e = (int)(tid >> 7);
    if (e >= E) return;
    int d = (int)(tid & 127);
    int src = ei[e];
    int dst = ei[E + e];
    float fs = feat[(size_t)src * D + d];
    float fd = feat[(size_t)dst * D + d];
    atomicAdd(&nsum[(size_t)src * D + d], fd);
    atomicAdd(&nsum[(size_t)dst * D + d], fs);
    if (d == 0) {
        atomicAdd(&cnt[src], 1.0f);
        atomicAdd(&cnt[dst], 1.0f);
    }
}

__global__ __launch_bounds__(256) void sage_out(
    const int* __restrict__ nodes, const float* __restrict__ feat,
    const float* nsum, const float* __restrict__ cnt,
    const float* __restrict__ W, const float* __restrict__ b,
    float* out, int B) {
    __shared__ float comb[16][256];
    const int t = threadIdx.x;
    const int j = t & 127;
    const int rr = t >> 7;
    const int base = blockIdx.x * 16;
    for (int r = 0; r < 16; ++r) {
        int row = base + r;
        float v = 0.0f;
        if (row < B) {
            int node = nodes[row];
            if (t < 128) {
                v = feat[(size_t)node * D + t];
            } else {
                float c = cnt[node];
                float inv = 1.0f / fmaxf(c, 1.0f);
                v = nsum[(size_t)node * D + (t - 128)] * inv;
            }
        }
        comb[r][t] = v;
    }
    __syncthreads();
    float acc[8];
    const float bj = b[j];
#pragma unroll
    for (int r = 0; r < 8; ++r) acc[r] = bj;
#pragma unroll 4
    for (int k = 0; k < 256; ++k) {
        float wj = W[(size_t)k * 128 + j];
#pragma unroll
        for (int r = 0; r < 8; ++r) acc[r] += comb[rr + 2 * r][k] * wj;
    }
#pragma unroll
    for (int r = 0; r < 8; ++r) {
        int row = base + rr + 2 * r;
        if (row < B) out[(size_t)row * D + j] = fmaxf(acc[r], 0.0f);
    }
}

extern "C" void kernel_launch(void* const* d_in, const int* in_sizes, int n_in,
                              void* d_out, int out_size, void* d_ws, size_t ws_size,
                              hipStream_t stream) {
    const int* nodes = (const int*)d_in[0];
    const float* feat = (const float*)d_in[1];
    const int* ei = (const int*)d_in[2];
    const float* W = (const float*)d_in[3];
    const float* b = (const float*)d_in[4];
    float* out = (float*)d_out;

    const int B = in_sizes[0];       // 100000 output rows
    const int N = in_sizes[1] / D;   // 100000 feature rows
    const int E = in_sizes[2] / 2;   // 3.2M edges
    const int twoE = 2 * E;

    // ws layout (ints): deg[N] | rowptr[N+1] | cursor[N] | bsum[128] | col[2E]
    const size_t i_deg = 0;
    const size_t i_rowptr = i_deg + N;
    const size_t i_cursor = i_rowptr + (N + 1);
    const size_t i_bsum = i_cursor + N;
    const size_t i_col = i_bsum + 128;
    const size_t need_bytes = (i_col + (size_t)twoE) * sizeof(int);

    if (ws_size >= need_bytes) {
        int* wsI = (int*)d_ws;
        int* deg = wsI + i_deg;
        int* rowptr = wsI + i_rowptr;
        int* cursor = wsI + i_cursor;
        int* bsum = wsI + i_bsum;
        int* col = wsI + i_col;

        hipMemsetAsync(deg, 0, (size_t)N * sizeof(int), stream);

        int eblocks = (E + 255) / 256;
        degree_count<<<eblocks, 256, 0, stream>>>(ei, deg, E);

        int nscan = (N + 1023) / 1024;  // <=128 by layout
        scan_block<<<nscan, 256, 0, stream>>>(deg, rowptr, bsum, N);
        scan_aux<<<1, 64, 0, stream>>>(bsum, nscan);
        scan_finalize<<<(N + 255) / 256, 256, 0, stream>>>(rowptr, cursor, bsum, N, twoE);

        csr_fill<<<eblocks, 256, 0, stream>>>(ei, cursor, col, E);

        gather_gemm<<<(B + 15) / 16, 256, 0, stream>>>(nodes, feat, rowptr, col, W, b, out, B);
    } else {
        // Fallback: atomic scatter with d_out as accumulator (needs only cnt in ws).
        float* nsum = out;
        float* cnt = (float*)d_ws;
        hipMemsetAsync(d_out, 0, (size_t)N * D * sizeof(float), stream);
        hipMemsetAsync(d_ws, 0, (size_t)N * sizeof(float), stream);
        long long tot = (long long)E * 128;
        int blocks = (int)((tot + 255) / 256);
        edge_scatter<<<blocks, 256, 0, stream>>>(ei, feat, nsum, cnt, E);
        sage_out<<<(B + 15) / 16, 256, 0, stream>>>(nodes, feat, nsum, cnt, W, b, out, B);
    }
}

// Round 4
// 1111.006 us; speedup vs baseline: 2.7944x; 1.3427x over previous
//
#include <hip/hip_runtime.h>
#include <hip/hip_bf16.h>

#define D 128

// ---------------- Pass A: degree + per-edge rank (ILP x4) ----------------
// atomicAdd's return value IS the edge's within-node rank -> no fill atomics.
__global__ __launch_bounds__(256) void deg_rank(
    const int* __restrict__ ei, int* __restrict__ deg,
    int* __restrict__ rank_s, int* __restrict__ rank_d, int E) {
    int tid = blockIdx.x * blockDim.x + threadIdx.x;
    int stride = gridDim.x * blockDim.x;
    int e0 = tid, e1 = tid + stride, e2 = tid + 2 * stride, e3 = tid + 3 * stride;
    bool v0 = e0 < E, v1 = e1 < E, v2 = e2 < E, v3 = e3 < E;
    int s0 = 0, s1 = 0, s2 = 0, s3 = 0, d0 = 0, d1 = 0, d2 = 0, d3 = 0;
    if (v0) { s0 = ei[e0]; d0 = ei[E + e0]; }
    if (v1) { s1 = ei[e1]; d1 = ei[E + e1]; }
    if (v2) { s2 = ei[e2]; d2 = ei[E + e2]; }
    if (v3) { s3 = ei[e3]; d3 = ei[E + e3]; }
    int rs0 = 0, rs1 = 0, rs2 = 0, rs3 = 0, rd0 = 0, rd1 = 0, rd2 = 0, rd3 = 0;
    if (v0) rs0 = atomicAdd(&deg[s0], 1);
    if (v1) rs1 = atomicAdd(&deg[s1], 1);
    if (v2) rs2 = atomicAdd(&deg[s2], 1);
    if (v3) rs3 = atomicAdd(&deg[s3], 1);
    if (v0) rd0 = atomicAdd(&deg[d0], 1);
    if (v1) rd1 = atomicAdd(&deg[d1], 1);
    if (v2) rd2 = atomicAdd(&deg[d2], 1);
    if (v3) rd3 = atomicAdd(&deg[d3], 1);
    if (v0) { rank_s[e0] = rs0; rank_d[e0] = rd0; }
    if (v1) { rank_s[e1] = rs1; rank_d[e1] = rd1; }
    if (v2) { rank_s[e2] = rs2; rank_d[e2] = rd2; }
    if (v3) { rank_s[e3] = rs3; rank_d[e3] = rd3; }
}

// ---------------- scan (exclusive prefix over deg) ----------------
__global__ __launch_bounds__(256) void scan_block(
    const int* __restrict__ deg, int* __restrict__ rowptr,
    int* __restrict__ bsum, int N) {
    __shared__ int lds[256];
    const int t = threadIdx.x;
    const int base = blockIdx.x * 1024 + t * 4;
    int v[4];
#pragma unroll
    for (int k = 0; k < 4; ++k) v[k] = (base + k < N) ? deg[base + k] : 0;
    lds[t] = v[0] + v[1] + v[2] + v[3];
    __syncthreads();
    for (int off = 1; off < 256; off <<= 1) {
        int x = (t >= off) ? lds[t - off] : 0;
        __syncthreads();
        lds[t] += x;
        __syncthreads();
    }
    if (t == 255) bsum[blockIdx.x] = lds[255];
    int run = (t > 0) ? lds[t - 1] : 0;
#pragma unroll
    for (int k = 0; k < 4; ++k) {
        if (base + k < N) rowptr[base + k] = run;
        run += v[k];
    }
}

__global__ void scan_aux(int* __restrict__ bsum, int nb) {
    if (threadIdx.x == 0 && blockIdx.x == 0) {
        int run = 0;
        for (int i = 0; i < nb; ++i) {
            int v = bsum[i];
            bsum[i] = run;
            run += v;
        }
    }
}

__global__ __launch_bounds__(256) void scan_finalize(
    int* __restrict__ rowptr, int* __restrict__ cursor,
    const int* __restrict__ bsum, int N, int twoE) {
    int i = blockIdx.x * blockDim.x + threadIdx.x;
    if (i == 0) rowptr[N] = twoE;
    if (i >= N) return;
    int r = rowptr[i] + bsum[i >> 10];
    rowptr[i] = r;
    cursor[i] = r;
}

// ---------------- Pass B: atomic-free fill (ILP x4) ----------------
__global__ __launch_bounds__(256) void csr_fill2(
    const int* __restrict__ ei, const int* __restrict__ rowptr,
    const int* __restrict__ rank_s, const int* __restrict__ rank_d,
    int* __restrict__ col, int E) {
    int tid = blockIdx.x * blockDim.x + threadIdx.x;
    int stride = gridDim.x * blockDim.x;
#pragma unroll
    for (int q = 0; q < 4; ++q) {
        int e = tid + q * stride;
        if (e < E) {
            int src = ei[e];
            int dst = ei[E + e];
            col[rowptr[src] + rank_s[e]] = dst;
            col[rowptr[dst] + rank_d[e]] = src;
        }
    }
}

// ---------------- fused gather + mean + GEMM + bias + relu ----------------
// Gather: wave w (t>>6) owns nodes w, w+4, w+8, w+12; 64 lanes cover 128 dims
// via float2 (512B per wave instruction, wave-uniform neighbor loop).
// GEMM: j = t&127, rr = t>>7, 8 rows/thread, float4 LDS broadcast reads.
__global__ __launch_bounds__(256) void gather_gemm(
    const int* __restrict__ nodes, const float* __restrict__ feat,
    const int* __restrict__ rowptr, const int* __restrict__ col,
    const float* __restrict__ W, const float* __restrict__ b,
    float* __restrict__ out, int B) {
    __shared__ float comb[16][256];
    const int t = threadIdx.x;
    const int lane = t & 63;
    const int w = t >> 6;  // wave id 0..3
    const int base = blockIdx.x * 16;
    const float2* feat2 = (const float2*)feat;

    // Self features (float2).
    for (int idx = t; idx < 16 * 64; idx += 256) {
        int r = idx >> 6, l = idx & 63;
        int row = base + r;
        float2 v = make_float2(0.f, 0.f);
        if (row < B) v = feat2[(size_t)nodes[row] * 64 + l];
        comb[r][2 * l] = v.x;
        comb[r][2 * l + 1] = v.y;
    }

    // Neighbor means.
    for (int rq = 0; rq < 4; ++rq) {
        int rl = w + 4 * rq;
        int row = base + rl;
        float ax = 0.f, ay = 0.f, bx = 0.f, by = 0.f;
        float cx = 0.f, cy = 0.f, dx = 0.f, dy = 0.f;
        float inv = 0.f;
        if (row < B) {
            int node = nodes[row];
            int p0 = rowptr[node], p1 = rowptr[node + 1];
            int i = p0;
            for (; i + 3 < p1; i += 4) {
                int n0 = col[i], n1 = col[i + 1], n2 = col[i + 2], n3 = col[i + 3];
                float2 v0 = feat2[(size_t)n0 * 64 + lane];
                float2 v1 = feat2[(size_t)n1 * 64 + lane];
                float2 v2 = feat2[(size_t)n2 * 64 + lane];
                float2 v3 = feat2[(size_t)n3 * 64 + lane];
                ax += v0.x; ay += v0.y;
                bx += v1.x; by += v1.y;
                cx += v2.x; cy += v2.y;
                dx += v3.x; dy += v3.y;
            }
            for (; i < p1; ++i) {
                float2 v = feat2[(size_t)col[i] * 64 + lane];
                ax += v.x; ay += v.y;
            }
            int degn = p1 - p0;
            inv = (degn > 0) ? 1.0f / (float)degn : 0.0f;
        }
        comb[rl][128 + 2 * lane] = ((ax + bx) + (cx + dx)) * inv;
        comb[rl][128 + 2 * lane + 1] = ((ay + by) + (cy + dy)) * inv;
    }
    __syncthreads();

    const int j = t & 127;
    const int rr = t >> 7;
    float acc[8];
    const float bj = b[j];
#pragma unroll
    for (int r = 0; r < 8; ++r) acc[r] = bj;

    for (int k4 = 0; k4 < 64; ++k4) {
        float w0 = W[(size_t)(4 * k4 + 0) * 128 + j];
        float w1 = W[(size_t)(4 * k4 + 1) * 128 + j];
        float w2 = W[(size_t)(4 * k4 + 2) * 128 + j];
        float w3 = W[(size_t)(4 * k4 + 3) * 128 + j];
#pragma unroll
        for (int r = 0; r < 8; ++r) {
            float4 c = *(const float4*)&comb[2 * r + rr][4 * k4];
            acc[r] = fmaf(c.x, w0, acc[r]);
            acc[r] = fmaf(c.y, w1, acc[r]);
            acc[r] = fmaf(c.z, w2, acc[r]);
            acc[r] = fmaf(c.w, w3, acc[r]);
        }
    }

#pragma unroll
    for (int r = 0; r < 8; ++r) {
        int row = base + 2 * r + rr;
        if (row < B) out[(size_t)row * D + j] = fmaxf(acc[r], 0.0f);
    }
}

// ---------------- Tier-2 fill (round-3, atomic cursor) ----------------
__global__ __launch_bounds__(256) void csr_fill(
    const int* __restrict__ ei, int* __restrict__ cursor,
    int* __restrict__ col, int E) {
    int e = blockIdx.x * blockDim.x + threadIdx.x;
    if (e >= E) return;
    int src = ei[e];
    int dst = ei[E + e];
    int p = atomicAdd(&cursor[src], 1);
    col[p] = dst;
    int q = atomicAdd(&cursor[dst], 1);
    col[q] = src;
}

__global__ __launch_bounds__(256) void degree_count(
    const int* __restrict__ ei, int* __restrict__ deg, int E) {
    int e = blockIdx.x * blockDim.x + threadIdx.x;
    if (e >= E) return;
    atomicAdd(&deg[ei[e]], 1);
    atomicAdd(&deg[ei[E + e]], 1);
}

// ---------------- Tier-3 fallback (atomic scatter) ----------------
__global__ __launch_bounds__(256) void edge_scatter(
    const int* __restrict__ ei, const float* __restrict__ feat,
    float* __restrict__ nsum, float* __restrict__ cnt, int E) {
    long long tid = (long long)blockIdx.x * blockDim.x + threadIdx.x;
    int e = (int)(tid >> 7);
    if (e >= E) return;
    int d = (int)(tid & 127);
    int src = ei[e];
    int dst = ei[E + e];
    atomicAdd(&nsum[(size_t)src * D + d], feat[(size_t)dst * D + d]);
    atomicAdd(&nsum[(size_t)dst * D + d], feat[(size_t)src * D + d]);
    if (d == 0) {
        atomicAdd(&cnt[src], 1.0f);
        atomicAdd(&cnt[dst], 1.0f);
    }
}

__global__ __launch_bounds__(256) void sage_out(
    const int* __restrict__ nodes, const float* __restrict__ feat,
    const float* nsum, const float* __restrict__ cnt,
    const float* __restrict__ W, const float* __restrict__ b,
    float* out, int B) {
    __shared__ float comb[16][256];
    const int t = threadIdx.x;
    const int j = t & 127;
    const int rr = t >> 7;
    const int base = blockIdx.x * 16;
    for (int r = 0; r < 16; ++r) {
        int row = base + r;
        float v = 0.0f;
        if (row < B) {
            int node = nodes[row];
            if (t < 128) {
                v = feat[(size_t)node * D + t];
            } else {
                v = nsum[(size_t)node * D + (t - 128)] / fmaxf(cnt[node], 1.0f);
            }
        }
        comb[r][t] = v;
    }
    __syncthreads();
    float acc[8];
    const float bj = b[j];
#pragma unroll
    for (int r = 0; r < 8; ++r) acc[r] = bj;
#pragma unroll 4
    for (int k = 0; k < 256; ++k) {
        float wj = W[(size_t)k * 128 + j];
#pragma unroll
        for (int r = 0; r < 8; ++r) acc[r] += comb[rr + 2 * r][k] * wj;
    }
#pragma unroll
    for (int r = 0; r < 8; ++r) {
        int row = base + rr + 2 * r;
        if (row < B) out[(size_t)row * D + j] = fmaxf(acc[r], 0.0f);
    }
}

extern "C" void kernel_launch(void* const* d_in, const int* in_sizes, int n_in,
                              void* d_out, int out_size, void* d_ws, size_t ws_size,
                              hipStream_t stream) {
    const int* nodes = (const int*)d_in[0];
    const float* feat = (const float*)d_in[1];
    const int* ei = (const int*)d_in[2];
    const float* W = (const float*)d_in[3];
    const float* b = (const float*)d_in[4];
    float* out = (float*)d_out;

    const int B = in_sizes[0];       // 100000
    const int N = in_sizes[1] / D;   // 100000
    const int E = in_sizes[2] / 2;   // 3.2M
    const int twoE = 2 * E;

    // Tier-1 layout (ints): deg[N] | rowptr[N+1] | bsum[128] | rank_s[E] | rank_d[E] | col[2E]
    const size_t o_deg = 0;
    const size_t o_rowptr = o_deg + N;
    const size_t o_bsum = o_rowptr + (N + 1);
    const size_t o_rank_s = o_bsum + 128;
    const size_t o_rank_d = o_rank_s + E;
    const size_t o_col1 = o_rank_d + E;
    const size_t need1 = (o_col1 + (size_t)twoE) * sizeof(int);

    // Tier-2 layout (ints): deg[N] | rowptr[N+1] | cursor[N] | bsum[128] | col[2E]
    const size_t t2_rowptr = (size_t)N;
    const size_t t2_cursor = t2_rowptr + (N + 1);
    const size_t t2_bsum = t2_cursor + N;
    const size_t t2_col = t2_bsum + 128;
    const size_t need2 = (t2_col + (size_t)twoE) * sizeof(int);

    const int nscan = (N + 1023) / 1024;

    if (ws_size >= need1) {
        int* wsI = (int*)d_ws;
        int* deg = wsI + o_deg;
        int* rowptr = wsI + o_rowptr;
        int* bsum = wsI + o_bsum;
        int* rank_s = wsI + o_rank_s;
        int* rank_d = wsI + o_rank_d;
        int* col = wsI + o_col1;

        hipMemsetAsync(deg, 0, (size_t)N * sizeof(int), stream);

        int eb4 = (E + 1023) / 1024;  // 4 edges per thread
        deg_rank<<<eb4, 256, 0, stream>>>(ei, deg, rank_s, rank_d, E);

        scan_block<<<nscan, 256, 0, stream>>>(deg, rowptr, bsum, N);
        scan_aux<<<1, 64, 0, stream>>>(bsum, nscan);
        // deg is dead after scan_block -> reuse as dummy cursor target.
        scan_finalize<<<(N + 255) / 256, 256, 0, stream>>>(rowptr, deg, bsum, N, twoE);

        csr_fill2<<<eb4, 256, 0, stream>>>(ei, rowptr, rank_s, rank_d, col, E);

        gather_gemm<<<(B + 15) / 16, 256, 0, stream>>>(nodes, feat, rowptr, col, W, b, out, B);
    } else if (ws_size >= need2) {
        int* wsI = (int*)d_ws;
        int* deg = wsI;
        int* rowptr = wsI + t2_rowptr;
        int* cursor = wsI + t2_cursor;
        int* bsum = wsI + t2_bsum;
        int* col = wsI + t2_col;

        hipMemsetAsync(deg, 0, (size_t)N * sizeof(int), stream);
        int eblocks = (E + 255) / 256;
        degree_count<<<eblocks, 256, 0, stream>>>(ei, deg, E);
        scan_block<<<nscan, 256, 0, stream>>>(deg, rowptr, bsum, N);
        scan_aux<<<1, 64, 0, stream>>>(bsum, nscan);
        scan_finalize<<<(N + 255) / 256, 256, 0, stream>>>(rowptr, cursor, bsum, N, twoE);
        csr_fill<<<eblocks, 256, 0, stream>>>(ei, cursor, col, E);
        gather_gemm<<<(B + 15) / 16, 256, 0, stream>>>(nodes, feat, rowptr, col, W, b, out, B);
    } else {
        float* nsum = out;
        float* cnt = (float*)d_ws;
        hipMemsetAsync(d_out, 0, (size_t)N * D * sizeof(float), stream);
        hipMemsetAsync(d_ws, 0, (size_t)N * sizeof(float), stream);
        long long tot = (long long)E * 128;
        int blocks = (int)((tot + 255) / 256);
        edge_scatter<<<blocks, 256, 0, stream>>>(ei, feat, nsum, cnt, E);
        sage_out<<<(B + 15) / 16, 256, 0, stream>>>(nodes, feat, nsum, cnt, W, b, out, B);
    }
}

// Round 5
// 843.599 us; speedup vs baseline: 3.6801x; 1.3170x over previous
//
#include <hip/hip_runtime.h>
#include <hip/hip_bf16.h>

#define D 128

__device__ __forceinline__ unsigned short f2bf(float f) {
    union { __hip_bfloat16 h; unsigned short u; } c;
    c.h = __float2bfloat16(f);  // round-to-nearest-even
    return c.u;
}

// ---------------- Pass A: degree + per-edge rank (ILP x8) ----------------
// atomicAdd's return value IS the edge's within-node rank -> no fill atomics.
__global__ __launch_bounds__(256) void deg_rank(
    const int* __restrict__ ei, int* __restrict__ deg,
    int2* __restrict__ rank2, int E) {
    int tid = blockIdx.x * blockDim.x + threadIdx.x;
    int stride = gridDim.x * blockDim.x;
    int e[8], s[8], d[8];
    bool v[8];
#pragma unroll
    for (int q = 0; q < 8; ++q) {
        e[q] = tid + q * stride;
        v[q] = e[q] < E;
    }
#pragma unroll
    for (int q = 0; q < 8; ++q) if (v[q]) { s[q] = ei[e[q]]; d[q] = ei[E + e[q]]; }
    int rs[8], rd[8];
#pragma unroll
    for (int q = 0; q < 8; ++q) if (v[q]) rs[q] = atomicAdd(&deg[s[q]], 1);
#pragma unroll
    for (int q = 0; q < 8; ++q) if (v[q]) rd[q] = atomicAdd(&deg[d[q]], 1);
#pragma unroll
    for (int q = 0; q < 8; ++q) if (v[q]) rank2[e[q]] = make_int2(rs[q], rd[q]);
}

// ---------------- scan (exclusive prefix over deg) ----------------
__global__ __launch_bounds__(256) void scan_block(
    const int* __restrict__ deg, int* __restrict__ rowptr,
    int* __restrict__ bsum, int N) {
    __shared__ int lds[256];
    const int t = threadIdx.x;
    const int base = blockIdx.x * 1024 + t * 4;
    int v[4];
#pragma unroll
    for (int k = 0; k < 4; ++k) v[k] = (base + k < N) ? deg[base + k] : 0;
    lds[t] = v[0] + v[1] + v[2] + v[3];
    __syncthreads();
    for (int off = 1; off < 256; off <<= 1) {
        int x = (t >= off) ? lds[t - off] : 0;
        __syncthreads();
        lds[t] += x;
        __syncthreads();
    }
    if (t == 255) bsum[blockIdx.x] = lds[255];
    int run = (t > 0) ? lds[t - 1] : 0;
#pragma unroll
    for (int k = 0; k < 4; ++k) {
        if (base + k < N) rowptr[base + k] = run;
        run += v[k];
    }
}

// Parallel exclusive scan of <=1024 block sums (Hillis-Steele in LDS).
__global__ __launch_bounds__(1024) void scan_aux(int* __restrict__ bsum, int nb) {
    __shared__ int lds[1024];
    const int t = threadIdx.x;
    int v = (t < nb) ? bsum[t] : 0;
    lds[t] = v;
    __syncthreads();
    for (int off = 1; off < 1024; off <<= 1) {
        int x = (t >= off) ? lds[t - off] : 0;
        __syncthreads();
        lds[t] += x;
        __syncthreads();
    }
    if (t < nb) bsum[t] = lds[t] - v;  // exclusive
}

__global__ __launch_bounds__(256) void scan_finalize(
    int* __restrict__ rowptr, const int* __restrict__ bsum, int N, int twoE) {
    int i = blockIdx.x * blockDim.x + threadIdx.x;
    if (i == 0) rowptr[N] = twoE;
    if (i >= N) return;
    rowptr[i] += bsum[i >> 10];
}

// ---------------- Pass B: atomic-free fill (ILP x4) ----------------
__global__ __launch_bounds__(256) void csr_fill2(
    const int* __restrict__ ei, const int* __restrict__ rowptr,
    const int2* __restrict__ rank2, int* __restrict__ col, int E) {
    int tid = blockIdx.x * blockDim.x + threadIdx.x;
    int stride = gridDim.x * blockDim.x;
    int e[4], s[4], d[4], ps[4], pd[4];
    int2 r2[4];
    bool v[4];
#pragma unroll
    for (int q = 0; q < 4; ++q) {
        e[q] = tid + q * stride;
        v[q] = e[q] < E;
    }
#pragma unroll
    for (int q = 0; q < 4; ++q) if (v[q]) { s[q] = ei[e[q]]; d[q] = ei[E + e[q]]; r2[q] = rank2[e[q]]; }
#pragma unroll
    for (int q = 0; q < 4; ++q) if (v[q]) { ps[q] = rowptr[s[q]]; pd[q] = rowptr[d[q]]; }
#pragma unroll
    for (int q = 0; q < 4; ++q) if (v[q]) {
        col[ps[q] + r2[q].x] = d[q];
        col[pd[q] + r2[q].y] = s[q];
    }
}

// ---------------- feat fp32 -> bf16 (RNE) ----------------
__global__ __launch_bounds__(256) void convert_bf16(
    const float4* __restrict__ f, uint2* __restrict__ o, int n4) {
    int i = blockIdx.x * blockDim.x + threadIdx.x;
    int stride = gridDim.x * blockDim.x;
    for (; i < n4; i += stride) {
        float4 v = f[i];
        uint2 r;
        r.x = (unsigned)f2bf(v.x) | ((unsigned)f2bf(v.y) << 16);
        r.y = (unsigned)f2bf(v.z) | ((unsigned)f2bf(v.w) << 16);
        o[i] = r;
    }
}

// ---------------- fused gather + mean + GEMM + bias + relu ----------------
// Gather from bf16 feat copy. Wave w (t>>6) owns rows w, w+4, w+8, w+12.
// node is forced into SGPR via readfirstlane -> rowptr/col become scalar
// loads; 8 neighbors unrolled = 8 independent 256B vector loads in flight.
// bf16 pair decode: lo = u<<16, hi = u & 0xffff0000 (bit-pattern reinterpret).
__global__ __launch_bounds__(256) void gather_gemm(
    const int* __restrict__ nodes, const unsigned int* __restrict__ fbu,
    const int* __restrict__ rowptr, const int* __restrict__ col,
    const float* __restrict__ W, const float* __restrict__ b,
    float* __restrict__ out, int B) {
    __shared__ float comb[16][256];
    const int t = threadIdx.x;
    const int lane = t & 63;
    const int w = t >> 6;  // wave id 0..3
    const int base = blockIdx.x * 16;

    // Self features (bf16 pair per lane).
    for (int idx = t; idx < 16 * 64; idx += 256) {
        int r = idx >> 6, l = idx & 63;
        int row = base + r;
        unsigned u = 0;
        if (row < B) u = fbu[(size_t)nodes[row] * 64 + l];
        comb[r][2 * l] = __uint_as_float(u << 16);
        comb[r][2 * l + 1] = __uint_as_float(u & 0xffff0000u);
    }

    // Neighbor means: 4 rows per wave, sequential; 8-neighbor unrolled loop.
    for (int rq = 0; rq < 4; ++rq) {
        const int rl = w + 4 * rq;
        const int row = base + rl;
        float a0 = 0.f, a1 = 0.f, b0 = 0.f, b1 = 0.f;
        float c0 = 0.f, c1 = 0.f, d0 = 0.f, d1 = 0.f;
        float inv = 0.f;
        if (row < B) {
            const int node = __builtin_amdgcn_readfirstlane(nodes[row]);
            const int p0 = rowptr[node], p1 = rowptr[node + 1];
            int i = p0;
            for (; i + 7 < p1; i += 8) {
                int n0 = col[i], n1 = col[i + 1], n2 = col[i + 2], n3 = col[i + 3];
                int n4 = col[i + 4], n5 = col[i + 5], n6 = col[i + 6], n7 = col[i + 7];
                unsigned u0 = fbu[(size_t)n0 * 64 + lane];
                unsigned u1 = fbu[(size_t)n1 * 64 + lane];
                unsigned u2 = fbu[(size_t)n2 * 64 + lane];
                unsigned u3 = fbu[(size_t)n3 * 64 + lane];
                unsigned u4 = fbu[(size_t)n4 * 64 + lane];
                unsigned u5 = fbu[(size_t)n5 * 64 + lane];
                unsigned u6 = fbu[(size_t)n6 * 64 + lane];
                unsigned u7 = fbu[(size_t)n7 * 64 + lane];
                a0 += __uint_as_float(u0 << 16); a1 += __uint_as_float(u0 & 0xffff0000u);
                b0 += __uint_as_float(u1 << 16); b1 += __uint_as_float(u1 & 0xffff0000u);
                c0 += __uint_as_float(u2 << 16); c1 += __uint_as_float(u2 & 0xffff0000u);
                d0 += __uint_as_float(u3 << 16); d1 += __uint_as_float(u3 & 0xffff0000u);
                a0 += __uint_as_float(u4 << 16); a1 += __uint_as_float(u4 & 0xffff0000u);
                b0 += __uint_as_float(u5 << 16); b1 += __uint_as_float(u5 & 0xffff0000u);
                c0 += __uint_as_float(u6 << 16); c1 += __uint_as_float(u6 & 0xffff0000u);
                d0 += __uint_as_float(u7 << 16); d1 += __uint_as_float(u7 & 0xffff0000u);
            }
            for (; i < p1; ++i) {
                unsigned u = fbu[(size_t)col[i] * 64 + lane];
                a0 += __uint_as_float(u << 16);
                a1 += __uint_as_float(u & 0xffff0000u);
            }
            const int degn = p1 - p0;
            inv = (degn > 0) ? 1.0f / (float)degn : 0.0f;
        }
        float2 m;
        m.x = ((a0 + b0) + (c0 + d0)) * inv;
        m.y = ((a1 + b1) + (c1 + d1)) * inv;
        *(float2*)&comb[rl][128 + 2 * lane] = m;
    }
    __syncthreads();

    const int j = t & 127;
    const int rr = t >> 7;
    float acc[8];
    const float bj = b[j];
#pragma unroll
    for (int r = 0; r < 8; ++r) acc[r] = bj;

    for (int k4 = 0; k4 < 64; ++k4) {
        float w0 = W[(size_t)(4 * k4 + 0) * 128 + j];
        float w1 = W[(size_t)(4 * k4 + 1) * 128 + j];
        float w2 = W[(size_t)(4 * k4 + 2) * 128 + j];
        float w3 = W[(size_t)(4 * k4 + 3) * 128 + j];
#pragma unroll
        for (int r = 0; r < 8; ++r) {
            float4 c = *(const float4*)&comb[2 * r + rr][4 * k4];
            acc[r] = fmaf(c.x, w0, acc[r]);
            acc[r] = fmaf(c.y, w1, acc[r]);
            acc[r] = fmaf(c.z, w2, acc[r]);
            acc[r] = fmaf(c.w, w3, acc[r]);
        }
    }

#pragma unroll
    for (int r = 0; r < 8; ++r) {
        int row = base + 2 * r + rr;
        if (row < B) out[(size_t)row * D + j] = fmaxf(acc[r], 0.0f);
    }
}

// ---------------- fallback (atomic scatter, d_out as accumulator) ----------------
__global__ __launch_bounds__(256) void edge_scatter(
    const int* __restrict__ ei, const float* __restrict__ feat,
    float* __restrict__ nsum, float* __restrict__ cnt, int E) {
    long long tid = (long long)blockIdx.x * blockDim.x + threadIdx.x;
    int e = (int)(tid >> 7);
    if (e >= E) return;
    int d = (int)(tid & 127);
    int src = ei[e];
    int dst = ei[E + e];
    atomicAdd(&nsum[(size_t)src * D + d], feat[(size_t)dst * D + d]);
    atomicAdd(&nsum[(size_t)dst * D + d], feat[(size_t)src * D + d]);
    if (d == 0) {
        atomicAdd(&cnt[src], 1.0f);
        atomicAdd(&cnt[dst], 1.0f);
    }
}

__global__ __launch_bounds__(256) void sage_out(
    const int* __restrict__ nodes, const float* __restrict__ feat,
    const float* nsum, const float* __restrict__ cnt,
    const float* __restrict__ W, const float* __restrict__ b,
    float* out, int B) {
    __shared__ float comb[16][256];
    const int t = threadIdx.x;
    const int j = t & 127;
    const int rr = t >> 7;
    const int base = blockIdx.x * 16;
    for (int r = 0; r < 16; ++r) {
        int row = base + r;
        float v = 0.0f;
        if (row < B) {
            int node = nodes[row];
            if (t < 128) v = feat[(size_t)node * D + t];
            else v = nsum[(size_t)node * D + (t - 128)] / fmaxf(cnt[node], 1.0f);
        }
        comb[r][t] = v;
    }
    __syncthreads();
    float acc[8];
    const float bj = b[j];
#pragma unroll
    for (int r = 0; r < 8; ++r) acc[r] = bj;
#pragma unroll 4
    for (int k = 0; k < 256; ++k) {
        float wj = W[(size_t)k * 128 + j];
#pragma unroll
        for (int r = 0; r < 8; ++r) acc[r] += comb[rr + 2 * r][k] * wj;
    }
#pragma unroll
    for (int r = 0; r < 8; ++r) {
        int row = base + rr + 2 * r;
        if (row < B) out[(size_t)row * D + j] = fmaxf(acc[r], 0.0f);
    }
}

extern "C" void kernel_launch(void* const* d_in, const int* in_sizes, int n_in,
                              void* d_out, int out_size, void* d_ws, size_t ws_size,
                              hipStream_t stream) {
    const int* nodes = (const int*)d_in[0];
    const float* feat = (const float*)d_in[1];
    const int* ei = (const int*)d_in[2];
    const float* W = (const float*)d_in[3];
    const float* b = (const float*)d_in[4];
    float* out = (float*)d_out;

    const int B = in_sizes[0];       // 100000
    const int N = in_sizes[1] / D;   // 100000
    const int E = in_sizes[2] / 2;   // 3.2M
    const int twoE = 2 * E;
    const int nscan = (N + 1023) / 1024;

    // ws layout (ints, 16B-aligned sections):
    //   deg[N] | rowptr[N+1] | bsum[1024] | col[2E] | rank2[E] (int2)
    // featbf (N*64 ints of bf16 pairs) OVERLAYS rank2 (dead after csr_fill2).
    const size_t o_deg = 0;
    const size_t o_rowptr = (o_deg + N + 3) & ~(size_t)3;
    const size_t o_bsum = (o_rowptr + N + 1 + 3) & ~(size_t)3;
    const size_t o_col = (o_bsum + 1024 + 3) & ~(size_t)3;
    const size_t o_rank2 = (o_col + twoE + 3) & ~(size_t)3;
    const size_t tail = ((size_t)twoE > (size_t)N * 64) ? (size_t)twoE : (size_t)N * 64;
    const size_t need1 = (o_rank2 + tail) * sizeof(int);

    if (ws_size >= need1 && nscan <= 1024) {
        int* wsI = (int*)d_ws;
        int* deg = wsI + o_deg;
        int* rowptr = wsI + o_rowptr;
        int* bsum = wsI + o_bsum;
        int* col = wsI + o_col;
        int2* rank2 = (int2*)(wsI + o_rank2);
        unsigned int* fbu = (unsigned int*)(wsI + o_rank2);  // overlays rank2

        hipMemsetAsync(deg, 0, (size_t)N * sizeof(int), stream);

        int eb8 = (E + 2047) / 2048;  // 8 edges/thread
        deg_rank<<<eb8, 256, 0, stream>>>(ei, deg, rank2, E);

        scan_block<<<nscan, 256, 0, stream>>>(deg, rowptr, bsum, N);
        scan_aux<<<1, 1024, 0, stream>>>(bsum, nscan);
        scan_finalize<<<(N + 255) / 256, 256, 0, stream>>>(rowptr, bsum, N, twoE);

        int eb4 = (E + 1023) / 1024;  // 4 edges/thread
        csr_fill2<<<eb4, 256, 0, stream>>>(ei, rowptr, rank2, col, E);

        // rank2 dead; overlay with bf16 features.
        int n4 = N * (D / 4);
        convert_bf16<<<(n4 + 1023) / 1024, 256, 0, stream>>>(
            (const float4*)feat, (uint2*)fbu, n4);

        gather_gemm<<<(B + 15) / 16, 256, 0, stream>>>(nodes, fbu, rowptr, col, W, b, out, B);
    } else {
        float* nsum = out;
        float* cnt = (float*)d_ws;
        hipMemsetAsync(d_out, 0, (size_t)N * D * sizeof(float), stream);
        hipMemsetAsync(d_ws, 0, (size_t)N * sizeof(float), stream);
        long long tot = (long long)E * 128;
        int blocks = (int)((tot + 255) / 256);
        edge_scatter<<<blocks, 256, 0, stream>>>(ei, feat, nsum, cnt, E);
        sage_out<<<(B + 15) / 16, 256, 0, stream>>>(nodes, feat, nsum, cnt, W, b, out, B);
    }
}